// Round 9
// baseline (10654.501 us; speedup 1.0000x reference)
//
#include <hip/hip_runtime.h>
#include <hip/hip_bf16.h>

#define S_LEN 4096
#define D_DIM 512
#define H_NUM 8
#define DK_DIM 64
#define FF_DIM 2048
#define QLD 1536   // fused qkv row stride

typedef __attribute__((ext_vector_type(8))) short short8;
typedef __attribute__((ext_vector_type(4))) float f32x4;
typedef __attribute__((ext_vector_type(4))) ushort us4;

#if __has_builtin(__builtin_amdgcn_exp2f)
#define EXP2F __builtin_amdgcn_exp2f
#else
#define EXP2F exp2f
#endif

__device__ __forceinline__ ushort f2bf(float f) {
    union { float f; uint u; } v; v.f = f;
    uint r = v.u + 0x7FFF + ((v.u >> 16) & 1);
    return (ushort)(r >> 16);
}

__device__ __forceinline__ void gload_lds16(const void* g, void* l) {
    __builtin_amdgcn_global_load_lds(
        (const __attribute__((address_space(1))) void*)g,
        (__attribute__((address_space(3))) void*)l,
        16, 0, 0);
}

#define MFMA16(a, b, c) __builtin_amdgcn_mfma_f32_16x16x32_bf16(a, b, c, 0, 0, 0)

// ---------------------------------------------------------------------------
// One-launch prep: 6 weight transposes (fp32 [K][N] -> bf16 [N][K]) + bias
// concat + mask->additive-bias. Grid 3088.
// ---------------------------------------------------------------------------
__global__ __launch_bounds__(256) void prep_all(
    const float* __restrict__ wq, const float* __restrict__ wk,
    const float* __restrict__ wv, const float* __restrict__ wo,
    const float* __restrict__ w1, const float* __restrict__ w2,
    const float* __restrict__ bq, const float* __restrict__ bk,
    const float* __restrict__ bv, const int* __restrict__ mask,
    ushort* __restrict__ wqkvt, ushort* __restrict__ wot,
    ushort* __restrict__ w1t, ushort* __restrict__ w2t,
    float* __restrict__ bqkv, float* __restrict__ mbias)
{
    __shared__ float t[32][33];
    const int bid = blockIdx.x, tid = threadIdx.x;
    if (bid < 3072) {
        const float* src; ushort* dst; int K, N, tx, ty;
        if (bid < 1024) {
            int wsel = bid >> 8, id = bid & 255;
            src = wsel == 0 ? wq : wsel == 1 ? wk : wsel == 2 ? wv : wo;
            dst = wsel == 0 ? wqkvt : wsel == 1 ? wqkvt + 512 * 512
                : wsel == 2 ? wqkvt + 1024 * 512 : wot;
            K = 512; N = 512; tx = id & 15; ty = id >> 4;
        } else if (bid < 2048) {
            int id = bid - 1024; src = w1; dst = w1t;
            K = 512; N = 2048; tx = id & 63; ty = id >> 6;
        } else {
            int id = bid - 2048; src = w2; dst = w2t;
            K = 2048; N = 512; tx = id & 15; ty = id >> 4;
        }
        int gn = tx * 32, gk = ty * 32;
        int lx = tid & 31, ly = tid >> 5;
#pragma unroll
        for (int i = 0; i < 32; i += 8)
            t[ly + i][lx] = src[(size_t)(gk + ly + i) * N + gn + lx];
        __syncthreads();
#pragma unroll
        for (int i = 0; i < 32; i += 8)
            dst[(size_t)(gn + ly + i) * K + gk + lx] = f2bf(t[lx][ly + i]);
    } else {
        int i = (bid - 3072) * 256 + tid;
        if (i < 512)       bqkv[i] = bq[i];
        else if (i < 1024) bqkv[i] = bk[i - 512];
        else if (i < 1536) bqkv[i] = bv[i - 1024];
        mbias[i] = mask[i] ? 0.0f : -1e9f;
    }
}

// ---------------------------------------------------------------------------
// LN1: fp32 in -> bf16 out.
// ---------------------------------------------------------------------------
__global__ __launch_bounds__(256) void ln1_kernel(
    const float* __restrict__ x,
    const float* __restrict__ aP, const float* __restrict__ bP,
    ushort* __restrict__ out)
{
    const int row = blockIdx.x;
    const int d = threadIdx.x * 2;
    float2 v = *(const float2*)(x + (size_t)row * D_DIM + d);
    float sum = v.x + v.y;
    float sq  = v.x * v.x + v.y * v.y;
#pragma unroll
    for (int off = 1; off < 64; off <<= 1) {
        sum += __shfl_xor(sum, off);
        sq  += __shfl_xor(sq, off);
    }
    __shared__ float ssum[4], ssq[4];
    int wid = threadIdx.x >> 6;
    if ((threadIdx.x & 63) == 0) { ssum[wid] = sum; ssq[wid] = sq; }
    __syncthreads();
    sum = ssum[0] + ssum[1] + ssum[2] + ssum[3];
    sq  = ssq[0] + ssq[1] + ssq[2] + ssq[3];
    float mean = sum * (1.0f / D_DIM);
    float var  = (sq - (float)D_DIM * mean * mean) * (1.0f / (D_DIM - 1));
    var = fmaxf(var, 0.0f);
    float scale = aP[0] / (sqrtf(var) + 1e-6f);
    float beta  = bP[0];
    ushort2 o;
    o.x = f2bf((v.x - mean) * scale + beta);
    o.y = f2bf((v.y - mean) * scale + beta);
    *(ushort2*)(out + (size_t)row * D_DIM + d) = o;
}

// ---------------------------------------------------------------------------
// LN2 fused with wo split-K combine.
// ---------------------------------------------------------------------------
__global__ __launch_bounds__(256) void ln2_fused(
    const float* __restrict__ x, const float* __restrict__ bo,
    const float* __restrict__ p0, const float* __restrict__ p1,
    const float* __restrict__ aP, const float* __restrict__ bP,
    float* __restrict__ x2, ushort* __restrict__ h2)
{
    const int row = blockIdx.x;
    const int d = threadIdx.x * 2;
    const size_t idx = (size_t)row * D_DIM + d;
    float2 xv = *(const float2*)(x + idx);
    float2 a0 = *(const float2*)(p0 + idx);
    float2 a1 = *(const float2*)(p1 + idx);
    float2 bb = *(const float2*)(bo + d);
    float2 v;
    v.x = xv.x + a0.x + a1.x + bb.x;
    v.y = xv.y + a0.y + a1.y + bb.y;
    *(float2*)(x2 + idx) = v;
    float sum = v.x + v.y;
    float sq  = v.x * v.x + v.y * v.y;
#pragma unroll
    for (int off = 1; off < 64; off <<= 1) {
        sum += __shfl_xor(sum, off);
        sq  += __shfl_xor(sq, off);
    }
    __shared__ float ssum[4], ssq[4];
    int wid = threadIdx.x >> 6;
    if ((threadIdx.x & 63) == 0) { ssum[wid] = sum; ssq[wid] = sq; }
    __syncthreads();
    sum = ssum[0] + ssum[1] + ssum[2] + ssum[3];
    sq  = ssq[0] + ssq[1] + ssq[2] + ssq[3];
    float mean = sum * (1.0f / D_DIM);
    float var  = (sq - (float)D_DIM * mean * mean) * (1.0f / (D_DIM - 1));
    var = fmaxf(var, 0.0f);
    float scale = aP[0] / (sqrtf(var) + 1e-6f);
    float beta  = bP[0];
    ushort2 o;
    o.x = f2bf((v.x - mean) * scale + beta);
    o.y = f2bf((v.y - mean) * scale + beta);
    *(ushort2*)(h2 + idx) = o;
}

// ---------------------------------------------------------------------------
// 128x128 MFMA bf16 GEMM (qkv / ff1): 4 waves in 2x2, each 64x64.
// Register-prefetch pipeline, single-buffer LDS (32 KB).
// ---------------------------------------------------------------------------
__global__ __launch_bounds__(256) void gemm_mfma128(
    const ushort* __restrict__ A, const ushort* __restrict__ Bt,
    const float* __restrict__ bias,
    ushort* __restrict__ outB, ushort* __restrict__ outVT,
    int M, int N, int K, int relu)
{
    __shared__ union {
        struct { ushort As[2][128][32]; ushort Bs[2][128][32]; } s;  // 32 KB
        ushort Es[4][32][68];                                        // 17.4 KB
    } u;
    const int tid = threadIdx.x;
    const int w = tid >> 6, lane = tid & 63;
    const int l15 = lane & 15, quad = lane >> 4;
    const int wm = w >> 1, wn = w & 1;
    const int sw = (l15 >> 1) & 3;
    const int swc = ((lane & 3) ^ ((lane >> 3) & 3)) * 16;
    const int m0 = blockIdx.y * 128, n0 = blockIdx.x * 128;

    f32x4 acc[4][4] = {};

    const char* gA  = (const char*)(A  + (size_t)(m0 + 32 * w + (lane >> 2)) * K) + swc;
    const char* gA2 = gA + (size_t)16 * K * 2;
    const char* gB  = (const char*)(Bt + (size_t)(n0 + 32 * w + (lane >> 2)) * K) + swc;
    const char* gB2 = gB + (size_t)16 * K * 2;

    short8 ra[4], rb[4];
    auto preload = [&]() {
        ra[0] = *(const short8*)gA;        ra[1] = *(const short8*)gA2;
        ra[2] = *(const short8*)(gA + 64); ra[3] = *(const short8*)(gA2 + 64);
        rb[0] = *(const short8*)gB;        rb[1] = *(const short8*)gB2;
        rb[2] = *(const short8*)(gB + 64); rb[3] = *(const short8*)(gB2 + 64);
        gA += 128; gA2 += 128; gB += 128; gB2 += 128;
    };

    preload();
    const int nit = K >> 6;
    for (int t = 0; t < nit; ++t) {
        // regs -> LDS (same layout as global_load_lds: wave base + lane*16)
        *(short8*)(&u.s.As[0][32 * w][0]      + lane * 8) = ra[0];
        *(short8*)(&u.s.As[0][32 * w + 16][0] + lane * 8) = ra[1];
        *(short8*)(&u.s.As[1][32 * w][0]      + lane * 8) = ra[2];
        *(short8*)(&u.s.As[1][32 * w + 16][0] + lane * 8) = ra[3];
        *(short8*)(&u.s.Bs[0][32 * w][0]      + lane * 8) = rb[0];
        *(short8*)(&u.s.Bs[0][32 * w + 16][0] + lane * 8) = rb[1];
        *(short8*)(&u.s.Bs[1][32 * w][0]      + lane * 8) = rb[2];
        *(short8*)(&u.s.Bs[1][32 * w + 16][0] + lane * 8) = rb[3];
        __syncthreads();
        if (t + 1 < nit) preload();   // latency overlapped by compute below
#pragma unroll
        for (int ks = 0; ks < 2; ++ks) {
            short8 af[4], bf[4];
#pragma unroll
            for (int i = 0; i < 4; ++i) {
                af[i] = *(const short8*)&u.s.As[ks][64 * wm + i * 16 + l15][(quad ^ sw) * 8];
                bf[i] = *(const short8*)&u.s.Bs[ks][64 * wn + i * 16 + l15][(quad ^ sw) * 8];
            }
#pragma unroll
            for (int mt = 0; mt < 4; ++mt)
#pragma unroll
                for (int nt = 0; nt < 4; ++nt)
                    acc[mt][nt] = MFMA16(af[mt], bf[nt], acc[mt][nt]);
        }
        __syncthreads();   // all waves done reading before next ds_write round
    }

    if (outVT && n0 >= 1024) {   // V columns of fused QKV: write transposed
#pragma unroll
        for (int mt = 0; mt < 4; ++mt)
#pragma unroll
            for (int nt = 0; nt < 4; ++nt) {
                int nn = n0 + 64 * wn + nt * 16 + l15;
                int mmb = m0 + 64 * wm + mt * 16 + quad * 4;
                us4 pk;
#pragma unroll
                for (int r = 0; r < 4; ++r)
                    pk[r] = (short)f2bf(acc[mt][nt][r] + bias[nn]);
                *(us4*)(outVT + (size_t)(nn - 1024) * S_LEN + mmb) = pk;
            }
        return;
    }

    // bf16 out via per-wave LDS bounce (two 32-row rounds)
#pragma unroll
    for (int h = 0; h < 2; ++h) {
#pragma unroll
        for (int mt = 2 * h; mt < 2 * h + 2; ++mt)
#pragma unroll
            for (int nt = 0; nt < 4; ++nt)
#pragma unroll
                for (int r = 0; r < 4; ++r) {
                    float v = acc[mt][nt][r] + bias[n0 + 64 * wn + nt * 16 + l15];
                    if (relu) v = fmaxf(v, 0.0f);
                    u.Es[w][(mt & 1) * 16 + quad * 4 + r][nt * 16 + l15] = f2bf(v);
                }
        __syncthreads();
#pragma unroll
        for (int p2 = 0; p2 < 4; ++p2) {
            int row = p2 * 8 + (lane >> 3);
            int col = (lane & 7) * 8;
            short8 vv = *(const short8*)&u.Es[w][row][col];
            *(short8*)(outB + (size_t)(m0 + 64 * wm + h * 32 + row) * N
                             + n0 + 64 * wn + col) = vv;
        }
        __syncthreads();
    }
}

// ---------------------------------------------------------------------------
// 128x64 MFMA bf16 GEMM, split-K partial output only (wo / ff2).
// ---------------------------------------------------------------------------
__global__ __launch_bounds__(256) void gemm_mfma(
    const ushort* __restrict__ A, const ushort* __restrict__ Bt,
    float* __restrict__ outF,
    int M, int N, int K, int ksl)
{
    __shared__ ushort As[2][2][128][32];   // 32 KB
    __shared__ ushort Bs[2][2][64][32];    // 16 KB
    const int tid = threadIdx.x;
    const int w = tid >> 6, lane = tid & 63;
    const int l15 = lane & 15, quad = lane >> 4;
    const int sw = (l15 >> 1) & 3;
    const int swc = ((lane & 3) ^ ((lane >> 3) & 3)) * 16;
    const int m0 = blockIdx.y * 128, n0 = blockIdx.x * 64;
    const int kz = blockIdx.z;
    const int kbeg = kz * ksl;

    f32x4 acc[2][4] = {};

    const char* gA  = (const char*)(A  + (size_t)(m0 + 32 * w + (lane >> 2)) * K + kbeg) + swc;
    const char* gA2 = gA + (size_t)16 * K * 2;
    const char* gB  = (const char*)(Bt + (size_t)(n0 + 16 * w + (lane >> 2)) * K + kbeg) + swc;

    auto stage = [&](int b) {
        gload_lds16(gA,       &As[b][0][32 * w][0]);
        gload_lds16(gA + 64,  &As[b][1][32 * w][0]);
        gload_lds16(gA2,      &As[b][0][32 * w + 16][0]);
        gload_lds16(gA2 + 64, &As[b][1][32 * w + 16][0]);
        gload_lds16(gB,       &Bs[b][0][16 * w][0]);
        gload_lds16(gB + 64,  &Bs[b][1][16 * w][0]);
        gA += 128; gA2 += 128; gB += 128;
    };

    stage(0);
    const int nit = ksl >> 6;
    for (int t = 0; t < nit; ++t) {
        __syncthreads();
        if (t + 1 < nit) stage((t + 1) & 1);
        const int b = t & 1;
#pragma unroll
        for (int ks = 0; ks < 2; ++ks) {
            short8 a0 = *(const short8*)&As[b][ks][32 * w + l15][(quad ^ sw) * 8];
            short8 a1 = *(const short8*)&As[b][ks][32 * w + 16 + l15][(quad ^ sw) * 8];
            short8 b0 = *(const short8*)&Bs[b][ks][0 * 16 + l15][(quad ^ sw) * 8];
            short8 b1 = *(const short8*)&Bs[b][ks][1 * 16 + l15][(quad ^ sw) * 8];
            short8 b2 = *(const short8*)&Bs[b][ks][2 * 16 + l15][(quad ^ sw) * 8];
            short8 b3 = *(const short8*)&Bs[b][ks][3 * 16 + l15][(quad ^ sw) * 8];
            acc[0][0] = MFMA16(a0, b0, acc[0][0]);
            acc[0][1] = MFMA16(a0, b1, acc[0][1]);
            acc[0][2] = MFMA16(a0, b2, acc[0][2]);
            acc[0][3] = MFMA16(a0, b3, acc[0][3]);
            acc[1][0] = MFMA16(a1, b0, acc[1][0]);
            acc[1][1] = MFMA16(a1, b1, acc[1][1]);
            acc[1][2] = MFMA16(a1, b2, acc[1][2]);
            acc[1][3] = MFMA16(a1, b3, acc[1][3]);
        }
    }

    float* of = outF + (size_t)kz * M * N;
#pragma unroll
    for (int mt = 0; mt < 2; ++mt)
#pragma unroll
        for (int nt = 0; nt < 4; ++nt)
#pragma unroll
            for (int r = 0; r < 4; ++r) {
                int mm = m0 + 32 * w + mt * 16 + quad * 4 + r;
                int nn = n0 + nt * 16 + l15;
                of[(size_t)mm * N + nn] = acc[mt][nt][r];
            }
}

// ---------------------------------------------------------------------------
// MFMA bf16 flash attention v6: BARRIER-FREE main loop.
// All LDS regions are wave-private (wave w: Vt[w], Pld[w]); K and Q fragments
// live entirely in registers (global->reg, double-buffered prefetch for K/V).
// Block = 64 q x 1 head (grid 512, head = bid&7 for XCD L2 locality).
// Wave w owns keys 32w..32w+31 of each 128-key tile; cross-wave O/l reduction
// once at the end (single barrier).
// ---------------------------------------------------------------------------
__global__ __launch_bounds__(256, 2) void flash_mfma(
    const ushort* __restrict__ qkv, const ushort* __restrict__ vbt,
    const float* __restrict__ mbias, ushort* __restrict__ at_bf)
{
    __shared__ ushort Vt[4][64][32];     // 16 KB [wave][dk][key%32]  (private)
    __shared__ ushort Pld[4][64][40];    // 20 KB [wave][q][key pad40] (private)

    const int bid = blockIdx.x;
    const int head = bid & 7;
    const int q0 = (bid >> 3) * 64;
    const int tid = threadIdx.x;
    const int w = tid >> 6, lane = tid & 63;
    const int l15 = lane & 15, quad = lane >> 4;
    const int hoff = head * DK_DIM;
    const int sw = (l15 >> 1) & 3;
    const int swc = ((lane & 3) ^ ((lane >> 3) & 3)) * 16;

    // ---- Q fragments: direct global -> registers (B-operand layout)
    short8 qf[2][4];
#pragma unroll
    for (int ks = 0; ks < 2; ++ks)
#pragma unroll
        for (int nt = 0; nt < 4; ++nt)
            qf[ks][nt] = *(const short8*)(qkv
                + (size_t)(q0 + nt * 16 + l15) * QLD + hoff + ks * 32 + quad * 8);

    // K fragment base (A-operand layout: row = 32w + kh*16 + l15, dk = ks*32 + quad*8)
    const ushort* kb = qkv + (size_t)(32 * w + l15) * QLD + 512 + hoff + quad * 8;
    const char* gv0 = (const char*)(vbt + (size_t)(lane >> 2) * S_LEN + w * 32) + swc;

    short8 rk[2][4], rv[2][4];
    auto preloadK = [&](int b, int ktg) {
        const ushort* kp = kb + (size_t)ktg * QLD;
        rk[b][0] = *(const short8*)(kp);                        // ks0 kh0
        rk[b][1] = *(const short8*)(kp + (size_t)16 * QLD);     // ks0 kh1
        rk[b][2] = *(const short8*)(kp + 32);                   // ks1 kh0
        rk[b][3] = *(const short8*)(kp + (size_t)16 * QLD + 32);// ks1 kh1
    };
    auto preloadV = [&](int b, int ktg) {
        const char* gv = gv0 + ktg * 2;
        rv[b][0] = *(const short8*)gv;
        rv[b][1] = *(const short8*)(gv + (size_t)16 * S_LEN * 2);
        rv[b][2] = *(const short8*)(gv + (size_t)32 * S_LEN * 2);
        rv[b][3] = *(const short8*)(gv + (size_t)48 * S_LEN * 2);
    };
    preloadK(0, 0);
    preloadV(0, 0);

    const short8 ones = {0x3F80, 0x3F80, 0x3F80, 0x3F80,
                         0x3F80, 0x3F80, 0x3F80, 0x3F80};
    f32x4 oacc[4][4] = {};   // [mt_q][nt_dk]
    f32x4 lacc[4] = {};

    const int NIT = S_LEN / 128;
    for (int t = 0; t < NIT; ++t) {
        const int b = t & 1;
        const int ktg = t * 128;
        // stage V (wave-private; same-wave DS ordering makes this safe w/o barrier)
        *(short8*)(&Vt[w][0][0]  + lane * 8) = rv[b][0];
        *(short8*)(&Vt[w][16][0] + lane * 8) = rv[b][1];
        *(short8*)(&Vt[w][32][0] + lane * 8) = rv[b][2];
        *(short8*)(&Vt[w][48][0] + lane * 8) = rv[b][3];
        if (t + 1 < NIT) {                      // prefetch next K/V tiles
            preloadK(b ^ 1, (t + 1) * 128);
            preloadV(b ^ 1, (t + 1) * 128);
        }

        // ---- S^T = K @ Q^T per 16-key half; p = exp2(fma) -> Pld (private)
#pragma unroll
        for (int kh = 0; kh < 2; ++kh) {
            f32x4 sacc[4] = {};
#pragma unroll
            for (int nt = 0; nt < 4; ++nt) {
                sacc[nt] = MFMA16(rk[b][kh],     qf[0][nt], sacc[nt]);
                sacc[nt] = MFMA16(rk[b][2 + kh], qf[1][nt], sacc[nt]);
            }
            f32x4 mb = *(const f32x4*)&mbias[ktg + 32 * w + kh * 16 + quad * 4];
#pragma unroll
            for (int nt = 0; nt < 4; ++nt) {
                us4 pk;
#pragma unroll
                for (int r = 0; r < 4; ++r) {
                    float pv = EXP2F(fmaf(sacc[nt][r], 0.18033688011112042f, mb[r]));
                    pk[r] = (ushort)(__float_as_uint(pv) >> 16);
                }
                *(us4*)&Pld[w][nt * 16 + l15][kh * 16 + quad * 4] = pk;
            }
        }

        // ---- O += P @ V_strip ; l += P @ 1
        short8 bvr[4];
#pragma unroll
        for (int nt = 0; nt < 4; ++nt)
            bvr[nt] = *(const short8*)&Vt[w][nt * 16 + l15][(quad ^ sw) * 8];
#pragma unroll
        for (int mt = 0; mt < 4; ++mt) {
            short8 ap = *(const short8*)&Pld[w][mt * 16 + l15][quad * 8];
            lacc[mt] = MFMA16(ap, ones, lacc[mt]);
#pragma unroll
            for (int nt = 0; nt < 4; ++nt)
                oacc[mt][nt] = MFMA16(ap, bvr[nt], oacc[mt][nt]);
        }
    }

    __syncthreads();   // all waves out of the barrier-free main loop

    // ---- cross-wave reduction: O = sum_w oacc, l = sum_w lacc, write bf16
    float* Ored = (float*)&Pld[0][0][0];   // 64 x 68 fp32 (17.4 KB <= 20 KB)
    float* lred = (float*)&Vt[0][0][0];    // 256 fp32 (on Vt region)
    const int qloc = tid >> 4, dk4 = (tid & 15) * 4;
    if (l15 == 0) {
#pragma unroll
        for (int m2 = 0; m2 < 4; ++m2)
#pragma unroll
            for (int r = 0; r < 4; ++r)
                lred[w * 64 + m2 * 16 + quad * 4 + r] = lacc[m2][r];
    }
#pragma unroll
    for (int mt = 0; mt < 4; ++mt) {
        if (mt) __syncthreads();   // prev round reads done
#pragma unroll
        for (int nt = 0; nt < 4; ++nt)
#pragma unroll
            for (int r = 0; r < 4; ++r)
                Ored[(w * 16 + quad * 4 + r) * 68 + nt * 16 + l15] = oacc[mt][nt][r];
        __syncthreads();
        f32x4 s = *(const f32x4*)&Ored[qloc * 68 + dk4];
#pragma unroll
        for (int ww = 1; ww < 4; ++ww)
            s += *(const f32x4*)&Ored[(ww * 16 + qloc) * 68 + dk4];
        float l = lred[mt * 16 + qloc] + lred[64 + mt * 16 + qloc]
                + lred[128 + mt * 16 + qloc] + lred[192 + mt * 16 + qloc];
        float inv = 1.0f / l;
        us4 pk;
#pragma unroll
        for (int j = 0; j < 4; ++j) pk[j] = (short)f2bf(s[j] * inv);
        *(us4*)&at_bf[(size_t)(q0 + mt * 16 + qloc) * D_DIM + hoff + dk4] = pk;
    }
}

// ---------------------------------------------------------------------------
// ff2 split-K combine: out = x2 + b2[col] + p0 + p1 (fp32)
// ---------------------------------------------------------------------------
__global__ __launch_bounds__(256) void ff2_combine(
    const float* __restrict__ x2, const float* __restrict__ b2,
    const float* __restrict__ p0, const float* __restrict__ p1,
    float* __restrict__ out)
{
    size_t i = ((size_t)blockIdx.x * 256 + threadIdx.x) * 4;
    f32x4 a  = *(const f32x4*)(x2 + i);
    f32x4 q0 = *(const f32x4*)(p0 + i);
    f32x4 q1 = *(const f32x4*)(p1 + i);
    f32x4 bb = *(const f32x4*)(b2 + (int)(i & 511));
    f32x4 r = a + q0 + q1 + bb;
    *(f32x4*)(out + i) = r;
}

// ---------------------------------------------------------------------------
extern "C" void kernel_launch(void* const* d_in, const int* in_sizes, int n_in,
                              void* d_out, int out_size, void* d_ws, size_t ws_size,
                              hipStream_t stream) {
    (void)in_sizes; (void)n_in; (void)out_size; (void)ws_size;
    const float* x    = (const float*)d_in[0];
    const int*   mask = (const int*)d_in[1];
    const float* wq = (const float*)d_in[2];
    const float* bq = (const float*)d_in[3];
    const float* wk = (const float*)d_in[4];
    const float* bk = (const float*)d_in[5];
    const float* wv = (const float*)d_in[6];
    const float* bv = (const float*)d_in[7];
    const float* wo = (const float*)d_in[8];
    const float* bo = (const float*)d_in[9];
    const float* w1 = (const float*)d_in[10];
    const float* b1 = (const float*)d_in[11];
    const float* w2 = (const float*)d_in[12];
    const float* b2 = (const float*)d_in[13];
    const float* ln1a = (const float*)d_in[14];
    const float* ln1b = (const float*)d_in[15];
    const float* ln2a = (const float*)d_in[16];
    const float* ln2b = (const float*)d_in[17];
    float* out = (float*)d_out;

    const size_t SD = (size_t)S_LEN * D_DIM;
    char* p = (char*)d_ws;
    ushort* wqkvt = (ushort*)p; p += (size_t)1536 * 512 * 2;
    ushort* wot   = (ushort*)p; p += (size_t)512 * 512 * 2;
    ushort* w1t   = (ushort*)p; p += (size_t)2048 * 512 * 2;
    ushort* w2t   = (ushort*)p; p += (size_t)512 * 2048 * 2;
    float*  bqkv  = (float*)p;  p += 1536 * 4;
    float*  mbias = (float*)p;  p += 4096 * 4;
    ushort* h_bf  = (ushort*)p; p += SD * 2;
    ushort* qkv   = (ushort*)p; p += (size_t)4096 * 1536 * 2;
    ushort* vbt   = (ushort*)p; p += SD * 2;
    ushort* at_bf = (ushort*)p; p += SD * 2;
    float*  x2    = (float*)p;  p += SD * 4;
    ushort* h2    = (ushort*)p; p += SD * 2;
    ushort* ff1   = (ushort*)p; p += (size_t)4096 * 2048 * 2;
    float* wopart  = (float*)h_bf;    // wo partials: 2 x SD fp32 (h_bf+qkv region)
    float* ff2part = (float*)h_bf;    // ff2 partials: 2 x SD fp32

    dim3 blk(256);

    prep_all<<<dim3(3088), blk, 0, stream>>>(wq, wk, wv, wo, w1, w2, bq, bk, bv,
                                             mask, wqkvt, wot, w1t, w2t, bqkv, mbias);

    ln1_kernel<<<dim3(S_LEN), blk, 0, stream>>>(x, ln1a, ln1b, h_bf);

    // fused QKV projection, 128x128 tiles (V written transposed to vbt)
    gemm_mfma128<<<dim3(12, 32), blk, 0, stream>>>(
        h_bf, wqkvt, bqkv, qkv, vbt, S_LEN, 1536, 512, 0);

    // flash attention v6 (barrier-free main loop)
    flash_mfma<<<dim3(512), blk, 0, stream>>>(qkv, vbt, mbias, at_bf);

    // output projection, split-K x2 -> partials
    gemm_mfma<<<dim3(8, 32, 2), blk, 0, stream>>>(
        at_bf, wot, wopart, S_LEN, 512, 512, 256);

    // x2 = x + bo + partials ; h2 = LN(x2)
    ln2_fused<<<dim3(S_LEN), blk, 0, stream>>>(x, bo, wopart, wopart + SD,
                                               ln2a, ln2b, x2, h2);

    // FFN-1 (relu), 128x128 tiles
    gemm_mfma128<<<dim3(16, 32), blk, 0, stream>>>(
        h2, w1t, b1, ff1, nullptr, S_LEN, 2048, 512, 1);

    // FFN-2 split-K x2 -> partials
    gemm_mfma<<<dim3(8, 32, 2), blk, 0, stream>>>(
        ff1, w2t, ff2part, S_LEN, 512, 2048, 1024);

    // out = x2 + b2 + p0 + p1
    ff2_combine<<<dim3(2048), blk, 0, stream>>>(
        x2, b2, ff2part, ff2part + SD, out);
}

// Round 10
// 227.857 us; speedup vs baseline: 46.7597x; 46.7597x over previous
//
#include <hip/hip_runtime.h>
#include <hip/hip_bf16.h>

#define S_LEN 4096
#define D_DIM 512
#define H_NUM 8
#define DK_DIM 64
#define FF_DIM 2048
#define QLD 1536   // fused qkv row stride

typedef __attribute__((ext_vector_type(8))) short short8;
typedef __attribute__((ext_vector_type(4))) float f32x4;
typedef __attribute__((ext_vector_type(4))) ushort us4;

#if __has_builtin(__builtin_amdgcn_exp2f)
#define EXP2F __builtin_amdgcn_exp2f
#else
#define EXP2F exp2f
#endif

__device__ __forceinline__ ushort f2bf(float f) {
    union { float f; uint u; } v; v.f = f;
    uint r = v.u + 0x7FFF + ((v.u >> 16) & 1);
    return (ushort)(r >> 16);
}

__device__ __forceinline__ void gload_lds16(const void* g, void* l) {
    __builtin_amdgcn_global_load_lds(
        (const __attribute__((address_space(1))) void*)g,
        (__attribute__((address_space(3))) void*)l,
        16, 0, 0);
}

#define MFMA16(a, b, c) __builtin_amdgcn_mfma_f32_16x16x32_bf16(a, b, c, 0, 0, 0)

// ---------------------------------------------------------------------------
// One-launch prep: 6 weight transposes (fp32 [K][N] -> bf16 [N][K]) + bias
// concat + mask->additive-bias. Grid 3088.
// ---------------------------------------------------------------------------
__global__ __launch_bounds__(256) void prep_all(
    const float* __restrict__ wq, const float* __restrict__ wk,
    const float* __restrict__ wv, const float* __restrict__ wo,
    const float* __restrict__ w1, const float* __restrict__ w2,
    const float* __restrict__ bq, const float* __restrict__ bk,
    const float* __restrict__ bv, const int* __restrict__ mask,
    ushort* __restrict__ wqkvt, ushort* __restrict__ wot,
    ushort* __restrict__ w1t, ushort* __restrict__ w2t,
    float* __restrict__ bqkv, float* __restrict__ mbias)
{
    __shared__ float t[32][33];
    const int bid = blockIdx.x, tid = threadIdx.x;
    if (bid < 3072) {
        const float* src; ushort* dst; int K, N, tx, ty;
        if (bid < 1024) {
            int wsel = bid >> 8, id = bid & 255;
            src = wsel == 0 ? wq : wsel == 1 ? wk : wsel == 2 ? wv : wo;
            dst = wsel == 0 ? wqkvt : wsel == 1 ? wqkvt + 512 * 512
                : wsel == 2 ? wqkvt + 1024 * 512 : wot;
            K = 512; N = 512; tx = id & 15; ty = id >> 4;
        } else if (bid < 2048) {
            int id = bid - 1024; src = w1; dst = w1t;
            K = 512; N = 2048; tx = id & 63; ty = id >> 6;
        } else {
            int id = bid - 2048; src = w2; dst = w2t;
            K = 2048; N = 512; tx = id & 15; ty = id >> 4;
        }
        int gn = tx * 32, gk = ty * 32;
        int lx = tid & 31, ly = tid >> 5;
#pragma unroll
        for (int i = 0; i < 32; i += 8)
            t[ly + i][lx] = src[(size_t)(gk + ly + i) * N + gn + lx];
        __syncthreads();
#pragma unroll
        for (int i = 0; i < 32; i += 8)
            dst[(size_t)(gn + ly + i) * K + gk + lx] = f2bf(t[lx][ly + i]);
    } else {
        int i = (bid - 3072) * 256 + tid;
        if (i < 512)       bqkv[i] = bq[i];
        else if (i < 1024) bqkv[i] = bk[i - 512];
        else if (i < 1536) bqkv[i] = bv[i - 1024];
        mbias[i] = mask[i] ? 0.0f : -1e9f;
    }
}

// ---------------------------------------------------------------------------
// LN1: fp32 in -> bf16 out.
// ---------------------------------------------------------------------------
__global__ __launch_bounds__(256) void ln1_kernel(
    const float* __restrict__ x,
    const float* __restrict__ aP, const float* __restrict__ bP,
    ushort* __restrict__ out)
{
    const int row = blockIdx.x;
    const int d = threadIdx.x * 2;
    float2 v = *(const float2*)(x + (size_t)row * D_DIM + d);
    float sum = v.x + v.y;
    float sq  = v.x * v.x + v.y * v.y;
#pragma unroll
    for (int off = 1; off < 64; off <<= 1) {
        sum += __shfl_xor(sum, off);
        sq  += __shfl_xor(sq, off);
    }
    __shared__ float ssum[4], ssq[4];
    int wid = threadIdx.x >> 6;
    if ((threadIdx.x & 63) == 0) { ssum[wid] = sum; ssq[wid] = sq; }
    __syncthreads();
    sum = ssum[0] + ssum[1] + ssum[2] + ssum[3];
    sq  = ssq[0] + ssq[1] + ssq[2] + ssq[3];
    float mean = sum * (1.0f / D_DIM);
    float var  = (sq - (float)D_DIM * mean * mean) * (1.0f / (D_DIM - 1));
    var = fmaxf(var, 0.0f);
    float scale = aP[0] / (sqrtf(var) + 1e-6f);
    float beta  = bP[0];
    ushort2 o;
    o.x = f2bf((v.x - mean) * scale + beta);
    o.y = f2bf((v.y - mean) * scale + beta);
    *(ushort2*)(out + (size_t)row * D_DIM + d) = o;
}

// ---------------------------------------------------------------------------
// LN2 fused with wo split-K combine.
// ---------------------------------------------------------------------------
__global__ __launch_bounds__(256) void ln2_fused(
    const float* __restrict__ x, const float* __restrict__ bo,
    const float* __restrict__ p0, const float* __restrict__ p1,
    const float* __restrict__ aP, const float* __restrict__ bP,
    float* __restrict__ x2, ushort* __restrict__ h2)
{
    const int row = blockIdx.x;
    const int d = threadIdx.x * 2;
    const size_t idx = (size_t)row * D_DIM + d;
    float2 xv = *(const float2*)(x + idx);
    float2 a0 = *(const float2*)(p0 + idx);
    float2 a1 = *(const float2*)(p1 + idx);
    float2 bb = *(const float2*)(bo + d);
    float2 v;
    v.x = xv.x + a0.x + a1.x + bb.x;
    v.y = xv.y + a0.y + a1.y + bb.y;
    *(float2*)(x2 + idx) = v;
    float sum = v.x + v.y;
    float sq  = v.x * v.x + v.y * v.y;
#pragma unroll
    for (int off = 1; off < 64; off <<= 1) {
        sum += __shfl_xor(sum, off);
        sq  += __shfl_xor(sq, off);
    }
    __shared__ float ssum[4], ssq[4];
    int wid = threadIdx.x >> 6;
    if ((threadIdx.x & 63) == 0) { ssum[wid] = sum; ssq[wid] = sq; }
    __syncthreads();
    sum = ssum[0] + ssum[1] + ssum[2] + ssum[3];
    sq  = ssq[0] + ssq[1] + ssq[2] + ssq[3];
    float mean = sum * (1.0f / D_DIM);
    float var  = (sq - (float)D_DIM * mean * mean) * (1.0f / (D_DIM - 1));
    var = fmaxf(var, 0.0f);
    float scale = aP[0] / (sqrtf(var) + 1e-6f);
    float beta  = bP[0];
    ushort2 o;
    o.x = f2bf((v.x - mean) * scale + beta);
    o.y = f2bf((v.y - mean) * scale + beta);
    *(ushort2*)(h2 + idx) = o;
}

// ---------------------------------------------------------------------------
// 128x128 MFMA bf16 GEMM (qkv / ff1): 4 waves in 2x2, each 64x64.
// Register-prefetch pipeline, single-buffer LDS (32 KB).
// ---------------------------------------------------------------------------
__global__ __launch_bounds__(256) void gemm_mfma128(
    const ushort* __restrict__ A, const ushort* __restrict__ Bt,
    const float* __restrict__ bias,
    ushort* __restrict__ outB, ushort* __restrict__ outVT,
    int M, int N, int K, int relu)
{
    __shared__ union {
        struct { ushort As[2][128][32]; ushort Bs[2][128][32]; } s;  // 32 KB
        ushort Es[4][32][68];                                        // 17.4 KB
    } u;
    const int tid = threadIdx.x;
    const int w = tid >> 6, lane = tid & 63;
    const int l15 = lane & 15, quad = lane >> 4;
    const int wm = w >> 1, wn = w & 1;
    const int sw = (l15 >> 1) & 3;
    const int swc = ((lane & 3) ^ ((lane >> 3) & 3)) * 16;
    const int m0 = blockIdx.y * 128, n0 = blockIdx.x * 128;

    f32x4 acc[4][4] = {};

    const char* gA  = (const char*)(A  + (size_t)(m0 + 32 * w + (lane >> 2)) * K) + swc;
    const char* gA2 = gA + (size_t)16 * K * 2;
    const char* gB  = (const char*)(Bt + (size_t)(n0 + 32 * w + (lane >> 2)) * K) + swc;
    const char* gB2 = gB + (size_t)16 * K * 2;

    short8 ra[4], rb[4];
    auto preload = [&]() {
        ra[0] = *(const short8*)gA;        ra[1] = *(const short8*)gA2;
        ra[2] = *(const short8*)(gA + 64); ra[3] = *(const short8*)(gA2 + 64);
        rb[0] = *(const short8*)gB;        rb[1] = *(const short8*)gB2;
        rb[2] = *(const short8*)(gB + 64); rb[3] = *(const short8*)(gB2 + 64);
        gA += 128; gA2 += 128; gB += 128; gB2 += 128;
    };

    preload();
    const int nit = K >> 6;
    for (int t = 0; t < nit; ++t) {
        // regs -> LDS (same layout as global_load_lds: wave base + lane*16)
        *(short8*)(&u.s.As[0][32 * w][0]      + lane * 8) = ra[0];
        *(short8*)(&u.s.As[0][32 * w + 16][0] + lane * 8) = ra[1];
        *(short8*)(&u.s.As[1][32 * w][0]      + lane * 8) = ra[2];
        *(short8*)(&u.s.As[1][32 * w + 16][0] + lane * 8) = ra[3];
        *(short8*)(&u.s.Bs[0][32 * w][0]      + lane * 8) = rb[0];
        *(short8*)(&u.s.Bs[0][32 * w + 16][0] + lane * 8) = rb[1];
        *(short8*)(&u.s.Bs[1][32 * w][0]      + lane * 8) = rb[2];
        *(short8*)(&u.s.Bs[1][32 * w + 16][0] + lane * 8) = rb[3];
        __syncthreads();
        if (t + 1 < nit) preload();   // latency overlapped by compute below
#pragma unroll
        for (int ks = 0; ks < 2; ++ks) {
            short8 af[4], bf[4];
#pragma unroll
            for (int i = 0; i < 4; ++i) {
                af[i] = *(const short8*)&u.s.As[ks][64 * wm + i * 16 + l15][(quad ^ sw) * 8];
                bf[i] = *(const short8*)&u.s.Bs[ks][64 * wn + i * 16 + l15][(quad ^ sw) * 8];
            }
#pragma unroll
            for (int mt = 0; mt < 4; ++mt)
#pragma unroll
                for (int nt = 0; nt < 4; ++nt)
                    acc[mt][nt] = MFMA16(af[mt], bf[nt], acc[mt][nt]);
        }
        __syncthreads();   // all waves done reading before next ds_write round
    }

    if (outVT && n0 >= 1024) {   // V columns of fused QKV: write transposed
#pragma unroll
        for (int mt = 0; mt < 4; ++mt)
#pragma unroll
            for (int nt = 0; nt < 4; ++nt) {
                int nn = n0 + 64 * wn + nt * 16 + l15;
                int mmb = m0 + 64 * wm + mt * 16 + quad * 4;
                us4 pk;
#pragma unroll
                for (int r = 0; r < 4; ++r)
                    pk[r] = (short)f2bf(acc[mt][nt][r] + bias[nn]);
                *(us4*)(outVT + (size_t)(nn - 1024) * S_LEN + mmb) = pk;
            }
        return;
    }

    // bf16 out via per-wave LDS bounce (two 32-row rounds)
#pragma unroll
    for (int h = 0; h < 2; ++h) {
#pragma unroll
        for (int mt = 2 * h; mt < 2 * h + 2; ++mt)
#pragma unroll
            for (int nt = 0; nt < 4; ++nt)
#pragma unroll
                for (int r = 0; r < 4; ++r) {
                    float v = acc[mt][nt][r] + bias[n0 + 64 * wn + nt * 16 + l15];
                    if (relu) v = fmaxf(v, 0.0f);
                    u.Es[w][(mt & 1) * 16 + quad * 4 + r][nt * 16 + l15] = f2bf(v);
                }
        __syncthreads();
#pragma unroll
        for (int p2 = 0; p2 < 4; ++p2) {
            int row = p2 * 8 + (lane >> 3);
            int col = (lane & 7) * 8;
            short8 vv = *(const short8*)&u.Es[w][row][col];
            *(short8*)(outB + (size_t)(m0 + 64 * wm + h * 32 + row) * N
                             + n0 + 64 * wn + col) = vv;
        }
        __syncthreads();
    }
}

// ---------------------------------------------------------------------------
// 128x64 MFMA bf16 GEMM, split-K partial output only (wo / ff2).
// ---------------------------------------------------------------------------
__global__ __launch_bounds__(256) void gemm_mfma(
    const ushort* __restrict__ A, const ushort* __restrict__ Bt,
    float* __restrict__ outF,
    int M, int N, int K, int ksl)
{
    __shared__ ushort As[2][2][128][32];   // 32 KB
    __shared__ ushort Bs[2][2][64][32];    // 16 KB
    const int tid = threadIdx.x;
    const int w = tid >> 6, lane = tid & 63;
    const int l15 = lane & 15, quad = lane >> 4;
    const int sw = (l15 >> 1) & 3;
    const int swc = ((lane & 3) ^ ((lane >> 3) & 3)) * 16;
    const int m0 = blockIdx.y * 128, n0 = blockIdx.x * 64;
    const int kz = blockIdx.z;
    const int kbeg = kz * ksl;

    f32x4 acc[2][4] = {};

    const char* gA  = (const char*)(A  + (size_t)(m0 + 32 * w + (lane >> 2)) * K + kbeg) + swc;
    const char* gA2 = gA + (size_t)16 * K * 2;
    const char* gB  = (const char*)(Bt + (size_t)(n0 + 16 * w + (lane >> 2)) * K + kbeg) + swc;

    auto stage = [&](int b) {
        gload_lds16(gA,       &As[b][0][32 * w][0]);
        gload_lds16(gA + 64,  &As[b][1][32 * w][0]);
        gload_lds16(gA2,      &As[b][0][32 * w + 16][0]);
        gload_lds16(gA2 + 64, &As[b][1][32 * w + 16][0]);
        gload_lds16(gB,       &Bs[b][0][16 * w][0]);
        gload_lds16(gB + 64,  &Bs[b][1][16 * w][0]);
        gA += 128; gA2 += 128; gB += 128;
    };

    stage(0);
    const int nit = ksl >> 6;
    for (int t = 0; t < nit; ++t) {
        __syncthreads();
        if (t + 1 < nit) stage((t + 1) & 1);
        const int b = t & 1;
#pragma unroll
        for (int ks = 0; ks < 2; ++ks) {
            short8 a0 = *(const short8*)&As[b][ks][32 * w + l15][(quad ^ sw) * 8];
            short8 a1 = *(const short8*)&As[b][ks][32 * w + 16 + l15][(quad ^ sw) * 8];
            short8 b0 = *(const short8*)&Bs[b][ks][0 * 16 + l15][(quad ^ sw) * 8];
            short8 b1 = *(const short8*)&Bs[b][ks][1 * 16 + l15][(quad ^ sw) * 8];
            short8 b2 = *(const short8*)&Bs[b][ks][2 * 16 + l15][(quad ^ sw) * 8];
            short8 b3 = *(const short8*)&Bs[b][ks][3 * 16 + l15][(quad ^ sw) * 8];
            acc[0][0] = MFMA16(a0, b0, acc[0][0]);
            acc[0][1] = MFMA16(a0, b1, acc[0][1]);
            acc[0][2] = MFMA16(a0, b2, acc[0][2]);
            acc[0][3] = MFMA16(a0, b3, acc[0][3]);
            acc[1][0] = MFMA16(a1, b0, acc[1][0]);
            acc[1][1] = MFMA16(a1, b1, acc[1][1]);
            acc[1][2] = MFMA16(a1, b2, acc[1][2]);
            acc[1][3] = MFMA16(a1, b3, acc[1][3]);
        }
    }

    float* of = outF + (size_t)kz * M * N;
#pragma unroll
    for (int mt = 0; mt < 2; ++mt)
#pragma unroll
        for (int nt = 0; nt < 4; ++nt)
#pragma unroll
            for (int r = 0; r < 4; ++r) {
                int mm = m0 + 32 * w + mt * 16 + quad * 4 + r;
                int nn = n0 + nt * 16 + l15;
                of[(size_t)mm * N + nn] = acc[mt][nt][r];
            }
}

// ---------------------------------------------------------------------------
// MFMA bf16 flash attention v7 = v5 structure with the two main-loop barriers
// REMOVED. All main-loop LDS regions are wave-private (wave w writes/reads
// only Ks rows 32w..32w+31, Vt[w], Pld[w]); same-wave DS ordering makes the
// loop barrier-free. Single-buffered reg-prefetch (rk[4], rv[4]) keeps VGPR
// at the v5 level (~104) — no spill. One barrier before cross-wave reduce.
// Block = 64 q x 1 head (grid 512, head = bid&7 for XCD L2 locality).
// ---------------------------------------------------------------------------
__global__ __launch_bounds__(256, 2) void flash_mfma(
    const ushort* __restrict__ qkv, const ushort* __restrict__ vbt,
    const float* __restrict__ mbias, ushort* __restrict__ at_bf)
{
    __shared__ ushort Ks[2][128][32];    // 16 KB [dkpanel][key][dk%32] (wave-private rows)
    __shared__ ushort Vt[4][64][32];     // 16 KB [wave][dk][key%32]
    __shared__ ushort Pld[4][64][40];    // 20 KB [wave][q][key pad40]

    const int bid = blockIdx.x;
    const int head = bid & 7;
    const int q0 = (bid >> 3) * 64;
    const int tid = threadIdx.x;
    const int w = tid >> 6, lane = tid & 63;
    const int l15 = lane & 15, quad = lane >> 4;
    const int hoff = head * DK_DIM;
    const int sw = (l15 >> 1) & 3;
    const int swc = ((lane & 3) ^ ((lane >> 3) & 3)) * 16;

    // ---- Q fragments: direct global -> registers (B-operand layout)
    short8 qf[2][4];
#pragma unroll
    for (int ks = 0; ks < 2; ++ks)
#pragma unroll
        for (int nt = 0; nt < 4; ++nt)
            qf[ks][nt] = *(const short8*)(qkv
                + (size_t)(q0 + nt * 16 + l15) * QLD + hoff + ks * 32 + quad * 8);

    const char* gk0 = (const char*)(qkv + (size_t)(32 * w + (lane >> 2)) * QLD + 512 + hoff) + swc;
    const char* gv0 = (const char*)(vbt + (size_t)(lane >> 2) * S_LEN + w * 32) + swc;

    short8 rk[4], rv[4];
    auto preload = [&](int ktg) {
        const char* gk = gk0 + (size_t)ktg * (QLD * 2);
        rk[0] = *(const short8*)gk;
        rk[1] = *(const short8*)(gk + (size_t)16 * QLD * 2);
        rk[2] = *(const short8*)(gk + 64);
        rk[3] = *(const short8*)(gk + (size_t)16 * QLD * 2 + 64);
        const char* gv = gv0 + ktg * 2;
        rv[0] = *(const short8*)gv;
        rv[1] = *(const short8*)(gv + (size_t)16 * S_LEN * 2);
        rv[2] = *(const short8*)(gv + (size_t)32 * S_LEN * 2);
        rv[3] = *(const short8*)(gv + (size_t)48 * S_LEN * 2);
    };
    preload(0);

    const short8 ones = {0x3F80, 0x3F80, 0x3F80, 0x3F80,
                         0x3F80, 0x3F80, 0x3F80, 0x3F80};
    f32x4 oacc[4][4] = {};   // [mt_q][nt_dk]
    f32x4 lacc[4] = {};

    const int NIT = S_LEN / 128;
    for (int t = 0; t < NIT; ++t) {
        // regs -> wave-private LDS; same-wave DS ordering, no barrier needed
        *(short8*)(&Ks[0][32 * w][0]      + lane * 8) = rk[0];
        *(short8*)(&Ks[0][32 * w + 16][0] + lane * 8) = rk[1];
        *(short8*)(&Ks[1][32 * w][0]      + lane * 8) = rk[2];
        *(short8*)(&Ks[1][32 * w + 16][0] + lane * 8) = rk[3];
        *(short8*)(&Vt[w][0][0]  + lane * 8) = rv[0];
        *(short8*)(&Vt[w][16][0] + lane * 8) = rv[1];
        *(short8*)(&Vt[w][32][0] + lane * 8) = rv[2];
        *(short8*)(&Vt[w][48][0] + lane * 8) = rv[3];
        if (t + 1 < NIT) preload((t + 1) * 128);   // overlapped with compute
        const int ktg = t * 128;

        // ---- S^T = K @ Q^T per 16-key half; p = exp2(fma) -> Pld
#pragma unroll
        for (int kh = 0; kh < 2; ++kh) {
            f32x4 sacc[4] = {};
#pragma unroll
            for (int ks = 0; ks < 2; ++ks) {
                short8 kf = *(const short8*)&Ks[ks][32 * w + kh * 16 + l15][(quad ^ sw) * 8];
#pragma unroll
                for (int nt = 0; nt < 4; ++nt)
                    sacc[nt] = MFMA16(kf, qf[ks][nt], sacc[nt]);
            }
            f32x4 mb = *(const f32x4*)&mbias[ktg + 32 * w + kh * 16 + quad * 4];
#pragma unroll
            for (int nt = 0; nt < 4; ++nt) {
                us4 pk;
#pragma unroll
                for (int r = 0; r < 4; ++r) {
                    float pv = EXP2F(fmaf(sacc[nt][r], 0.18033688011112042f, mb[r]));
                    pk[r] = (ushort)(__float_as_uint(pv) >> 16);
                }
                *(us4*)&Pld[w][nt * 16 + l15][kh * 16 + quad * 4] = pk;
            }
        }

        // ---- O += P @ V_strip ; l += P @ 1 (V frags register-cached)
        short8 bvr[4];
#pragma unroll
        for (int nt = 0; nt < 4; ++nt)
            bvr[nt] = *(const short8*)&Vt[w][nt * 16 + l15][(quad ^ sw) * 8];
#pragma unroll
        for (int mt = 0; mt < 4; ++mt) {
            short8 ap = *(const short8*)&Pld[w][mt * 16 + l15][quad * 8];
            lacc[mt] = MFMA16(ap, ones, lacc[mt]);
#pragma unroll
            for (int nt = 0; nt < 4; ++nt)
                oacc[mt][nt] = MFMA16(ap, bvr[nt], oacc[mt][nt]);
        }
        // no barrier: next iteration's ds_writes are same-wave ordered
    }

    __syncthreads();   // all waves out of the barrier-free main loop

    // ---- cross-wave reduction: O = sum_w oacc, l = sum_w lacc, write bf16
    float* Ored = (float*)&Pld[0][0][0];   // 64 x 68 fp32 (17.4 KB <= 20 KB)
    float* lred = (float*)&Ks[0][0][0];    // 256 fp32
    const int qloc = tid >> 4, dk4 = (tid & 15) * 4;
    if (l15 == 0) {
#pragma unroll
        for (int m2 = 0; m2 < 4; ++m2)
#pragma unroll
            for (int r = 0; r < 4; ++r)
                lred[w * 64 + m2 * 16 + quad * 4 + r] = lacc[m2][r];
    }
#pragma unroll
    for (int mt = 0; mt < 4; ++mt) {
        if (mt) __syncthreads();   // prev round reads done
#pragma unroll
        for (int nt = 0; nt < 4; ++nt)
#pragma unroll
            for (int r = 0; r < 4; ++r)
                Ored[(w * 16 + quad * 4 + r) * 68 + nt * 16 + l15] = oacc[mt][nt][r];
        __syncthreads();
        f32x4 s = *(const f32x4*)&Ored[qloc * 68 + dk4];
#pragma unroll
        for (int ww = 1; ww < 4; ++ww)
            s += *(const f32x4*)&Ored[(ww * 16 + qloc) * 68 + dk4];
        float l = lred[mt * 16 + qloc] + lred[64 + mt * 16 + qloc]
                + lred[128 + mt * 16 + qloc] + lred[192 + mt * 16 + qloc];
        float inv = 1.0f / l;
        us4 pk;
#pragma unroll
        for (int j = 0; j < 4; ++j) pk[j] = (short)f2bf(s[j] * inv);
        *(us4*)&at_bf[(size_t)(q0 + mt * 16 + qloc) * D_DIM + hoff + dk4] = pk;
    }
}

// ---------------------------------------------------------------------------
// ff2 split-K combine: out = x2 + b2[col] + p0 + p1 (fp32)
// ---------------------------------------------------------------------------
__global__ __launch_bounds__(256) void ff2_combine(
    const float* __restrict__ x2, const float* __restrict__ b2,
    const float* __restrict__ p0, const float* __restrict__ p1,
    float* __restrict__ out)
{
    size_t i = ((size_t)blockIdx.x * 256 + threadIdx.x) * 4;
    f32x4 a  = *(const f32x4*)(x2 + i);
    f32x4 q0 = *(const f32x4*)(p0 + i);
    f32x4 q1 = *(const f32x4*)(p1 + i);
    f32x4 bb = *(const f32x4*)(b2 + (int)(i & 511));
    f32x4 r = a + q0 + q1 + bb;
    *(f32x4*)(out + i) = r;
}

// ---------------------------------------------------------------------------
extern "C" void kernel_launch(void* const* d_in, const int* in_sizes, int n_in,
                              void* d_out, int out_size, void* d_ws, size_t ws_size,
                              hipStream_t stream) {
    (void)in_sizes; (void)n_in; (void)out_size; (void)ws_size;
    const float* x    = (const float*)d_in[0];
    const int*   mask = (const int*)d_in[1];
    const float* wq = (const float*)d_in[2];
    const float* bq = (const float*)d_in[3];
    const float* wk = (const float*)d_in[4];
    const float* bk = (const float*)d_in[5];
    const float* wv = (const float*)d_in[6];
    const float* bv = (const float*)d_in[7];
    const float* wo = (const float*)d_in[8];
    const float* bo = (const float*)d_in[9];
    const float* w1 = (const float*)d_in[10];
    const float* b1 = (const float*)d_in[11];
    const float* w2 = (const float*)d_in[12];
    const float* b2 = (const float*)d_in[13];
    const float* ln1a = (const float*)d_in[14];
    const float* ln1b = (const float*)d_in[15];
    const float* ln2a = (const float*)d_in[16];
    const float* ln2b = (const float*)d_in[17];
    float* out = (float*)d_out;

    const size_t SD = (size_t)S_LEN * D_DIM;
    char* p = (char*)d_ws;
    ushort* wqkvt = (ushort*)p; p += (size_t)1536 * 512 * 2;
    ushort* wot   = (ushort*)p; p += (size_t)512 * 512 * 2;
    ushort* w1t   = (ushort*)p; p += (size_t)2048 * 512 * 2;
    ushort* w2t   = (ushort*)p; p += (size_t)512 * 2048 * 2;
    float*  bqkv  = (float*)p;  p += 1536 * 4;
    float*  mbias = (float*)p;  p += 4096 * 4;
    ushort* h_bf  = (ushort*)p; p += SD * 2;
    ushort* qkv   = (ushort*)p; p += (size_t)4096 * 1536 * 2;
    ushort* vbt   = (ushort*)p; p += SD * 2;
    ushort* at_bf = (ushort*)p; p += SD * 2;
    float*  x2    = (float*)p;  p += SD * 4;
    ushort* h2    = (ushort*)p; p += SD * 2;
    ushort* ff1   = (ushort*)p; p += (size_t)4096 * 2048 * 2;
    float* wopart  = (float*)h_bf;    // wo partials: 2 x SD fp32 (h_bf+qkv region)
    float* ff2part = (float*)h_bf;    // ff2 partials: 2 x SD fp32

    dim3 blk(256);

    prep_all<<<dim3(3088), blk, 0, stream>>>(wq, wk, wv, wo, w1, w2, bq, bk, bv,
                                             mask, wqkvt, wot, w1t, w2t, bqkv, mbias);

    ln1_kernel<<<dim3(S_LEN), blk, 0, stream>>>(x, ln1a, ln1b, h_bf);

    // fused QKV projection, 128x128 tiles (V written transposed to vbt)
    gemm_mfma128<<<dim3(12, 32), blk, 0, stream>>>(
        h_bf, wqkvt, bqkv, qkv, vbt, S_LEN, 1536, 512, 0);

    // flash attention v7 (barrier-free main loop, v5 register budget)
    flash_mfma<<<dim3(512), blk, 0, stream>>>(qkv, vbt, mbias, at_bf);

    // output projection, split-K x2 -> partials
    gemm_mfma<<<dim3(8, 32, 2), blk, 0, stream>>>(
        at_bf, wot, wopart, S_LEN, 512, 512, 256);

    // x2 = x + bo + partials ; h2 = LN(x2)
    ln2_fused<<<dim3(S_LEN), blk, 0, stream>>>(x, bo, wopart, wopart + SD,
                                               ln2a, ln2b, x2, h2);

    // FFN-1 (relu), 128x128 tiles
    gemm_mfma128<<<dim3(16, 32), blk, 0, stream>>>(
        h2, w1t, b1, ff1, nullptr, S_LEN, 2048, 512, 1);

    // FFN-2 split-K x2 -> partials
    gemm_mfma<<<dim3(8, 32, 2), blk, 0, stream>>>(
        ff1, w2t, ff2part, S_LEN, 512, 2048, 1024);

    // out = x2 + b2 + p0 + p1
    ff2_combine<<<dim3(2048), blk, 0, stream>>>(
        x2, b2, ff2part, ff2part + SD, out);
}